// Round 6
// baseline (130.527 us; speedup 1.0000x reference)
//
#include <hip/hip_runtime.h>
#include <math.h>

typedef _Float16 f16;
typedef _Float16 f16x8 __attribute__((ext_vector_type(8)));
typedef __bf16 bf16x8 __attribute__((ext_vector_type(8)));
typedef __bf16 bf16x8a4 __attribute__((ext_vector_type(8), aligned(4)));
typedef float f32x4 __attribute__((ext_vector_type(4)));

#define MFMA_F16(a, b, c)  __builtin_amdgcn_mfma_f32_16x16x32_f16(a, b, c, 0, 0, 0)
#define MFMA_BF16(a, b, c) __builtin_amdgcn_mfma_f32_16x16x32_bf16(a, b, c, 0, 0, 0)

// ---------------------------------------------------------------------------
// Fused producer. Blocks 0..1215: (b,g,hp) rows -> Q,K,V via f16 MFMA.
// Weights load straight to register fragments; only x^T staged in LDS.
// Block 1216 builds relp.
// Layouts: Qb f16 [pos][g*128 + head*32 + c]; Kb f16 [b][g][hp][wp][c];
//          VtA bf16 [b][g][c][hp][idx=wp (40)]; VtB same but idx = wp-1.
// ---------------------------------------------------------------------------
__global__ __launch_bounds__(256) void produce_kernel(
    const float* __restrict__ x,
    const float* __restrict__ wq, const float* __restrict__ bq,
    const float* __restrict__ wk, const float* __restrict__ bk,
    const float* __restrict__ wv, const float* __restrict__ bv,
    const float* __restrict__ rel_h, const float* __restrict__ rel_w,
    f16* __restrict__ Qb, f16* __restrict__ Kb,
    __bf16* __restrict__ VtA, __bf16* __restrict__ VtB,
    f16* __restrict__ relp) {
    int bid = blockIdx.x;
    int t = threadIdx.x;

    if (bid == 1216) {  // rel' table: key=(gp*7+kh)*8+kw, channel c
        for (int idx = t; idx < 448 * 32; idx += 256) {
            int c = idx & 31, key = idx >> 5;
            int kw = key & 7, ghk = key >> 3;
            int gp = (ghk * 37) >> 8;
            int kh = ghk - gp * 7;
            float v = 0.f;
            if (kw < 7)
                v = (c < 16) ? rel_h[c * 56 + gp * 7 + kh]
                             : rel_w[(c - 16) * 56 + gp * 7 + kw];
            relp[idx] = (f16)v;
        }
        return;
    }

    int hp = bid % 38, g = (bid / 38) & 7, b = bid / 304;
    bool hin = (hp >= 3 && hp < 35);
    size_t kvbase = (size_t)(b * 8 + g);

    if (!hin) {  // pure-bias row (h padding)
        for (int idx = t; idx < 38 * 32; idx += 256) {
            int wp = idx >> 5, c = idx & 31;
            Kb[((kvbase * 38 + hp) * 38 + wp) * 32 + c] = (f16)bk[g * 32 + c];
        }
        for (int idx = t; idx < 40 * 32; idx += 256) {
            int i = idx >> 5, c = idx & 31;
            size_t vo = ((kvbase * 32 + c) * 38 + hp) * 40;
            __bf16 bb = (__bf16)bv[g * 32 + c];
            VtA[vo + i] = (i < 38) ? bb : (__bf16)0.f;
            VtB[vo + i] = (i < 37) ? bb : (__bf16)0.f;  // idx i = wp i+1
        }
        return;
    }

    int h = hp - 3;
    __shared__ __align__(16) f16 xTl[32 * 40];  // [w][ic], stride 40

    {   // stage x^T (each thread one float4 along w)
        int ic = t >> 3, w = (t & 7) * 4;
        float4 xv = *(const float4*)(x + (((size_t)b * 256 + g * 32 + ic) * 32 + h) * 32 + w);
        xTl[(w + 0) * 40 + ic] = (f16)xv.x;
        xTl[(w + 1) * 40 + ic] = (f16)xv.y;
        xTl[(w + 2) * 40 + ic] = (f16)xv.z;
        xTl[(w + 3) * 40 + ic] = (f16)xv.w;
    }
    __syncthreads();

    int l15 = t & 15, quad = (t >> 4) & 3, wave = t >> 6;

    f16x8 a0 = *(const f16x8*)(xTl + l15 * 40 + quad * 8);
    f16x8 a1 = *(const f16x8*)(xTl + (16 + l15) * 40 + quad * 8);

    // ---- Q: wave covers Nt = wave*2 + {0,1} ----
#pragma unroll
    for (int i = 0; i < 2; ++i) {
        int Nt = wave * 2 + i;
        const float4* wp4 = (const float4*)(wq + ((size_t)g * 128 + Nt * 16 + l15) * 32 + quad * 8);
        float4 u0 = wp4[0], u1 = wp4[1];
        f16x8 bfrag;
        bfrag[0] = (f16)u0.x; bfrag[1] = (f16)u0.y; bfrag[2] = (f16)u0.z; bfrag[3] = (f16)u0.w;
        bfrag[4] = (f16)u1.x; bfrag[5] = (f16)u1.y; bfrag[6] = (f16)u1.z; bfrag[7] = (f16)u1.w;
        float bias = bq[g * 128 + Nt * 16 + l15];
#pragma unroll
        for (int Mt = 0; Mt < 2; ++Mt) {
            f32x4 d = {0.f, 0.f, 0.f, 0.f};
            d = MFMA_F16(Mt ? a1 : a0, bfrag, d);
#pragma unroll
            for (int r = 0; r < 4; ++r) {
                int w = Mt * 16 + quad * 4 + r;
                Qb[(size_t)((b * 32 + h) * 32 + w) * 1024 + g * 128 + Nt * 16 + l15] =
                    (f16)(d[r] + bias);
            }
        }
    }

    // ---- K/V: wave -> (sel, Nth) ----
    {
        int sel = wave & 1, Nth = wave >> 1;
        const float* wsrc = sel ? wv : wk;
        const float4* wp4 = (const float4*)(wsrc + ((size_t)g * 32 + Nth * 16 + l15) * 32 + quad * 8);
        float4 u0 = wp4[0], u1 = wp4[1];
        f16x8 bfrag;
        bfrag[0] = (f16)u0.x; bfrag[1] = (f16)u0.y; bfrag[2] = (f16)u0.z; bfrag[3] = (f16)u0.w;
        bfrag[4] = (f16)u1.x; bfrag[5] = (f16)u1.y; bfrag[6] = (f16)u1.z; bfrag[7] = (f16)u1.w;
        float bias = (sel ? bv : bk)[g * 32 + Nth * 16 + l15];
        int c = Nth * 16 + l15;
#pragma unroll
        for (int Mt = 0; Mt < 2; ++Mt) {
            f32x4 d = {0.f, 0.f, 0.f, 0.f};
            d = MFMA_F16(Mt ? a1 : a0, bfrag, d);
#pragma unroll
            for (int r = 0; r < 4; ++r) {
                int wp = Mt * 16 + quad * 4 + r + 3;
                float v = d[r] + bias;
                if (!sel) {
                    Kb[((kvbase * 38 + hp) * 38 + wp) * 32 + c] = (f16)v;
                } else {
                    size_t vo = ((kvbase * 32 + c) * 38 + hp) * 40;
                    VtA[vo + wp] = (__bf16)v;
                    VtB[vo + wp - 1] = (__bf16)v;
                }
            }
        }
    }

    // ---- wp borders (bias) + zero pads ----
    for (int idx = t; idx < 192; idx += 256) {
        int wi = idx >> 5, c = idx & 31;
        int wp = (wi < 3) ? wi : (32 + wi);  // {0,1,2,35,36,37}
        Kb[((kvbase * 38 + hp) * 38 + wp) * 32 + c] = (f16)bk[g * 32 + c];
        size_t vo = ((kvbase * 32 + c) * 38 + hp) * 40;
        __bf16 bb = (__bf16)bv[g * 32 + c];
        VtA[vo + wp] = bb;
        if (wp >= 1) VtB[vo + wp - 1] = bb;
    }
    for (int idx = t; idx < 160; idx += 256) {  // VtA idx 38,39; VtB idx 37,38,39
        int c = idx / 5, j = idx % 5;
        size_t vo = ((kvbase * 32 + c) * 38 + hp) * 40;
        if (j < 2) VtA[vo + 38 + j] = (__bf16)0.f;
        else       VtB[vo + 35 + j] = (__bf16)0.f;
    }
}

// ---------------------------------------------------------------------------
// MFMA attention: 128-thread blocks = 2 waves, one position per wave,
// barrier-free (Pl slices wave-private). LDS 17,408 B -> 9 blocks/CU
// (18 waves/CU).
// Softmax denominators via a constant "ones" PV n-tile (matrix pipe), kw=7
// masking via zeroed V fragment element 7 (not P) -> no per-element cndmask,
// no fsum VALU adds, no shuffle-reduce tree.
// ---------------------------------------------------------------------------
__global__ __launch_bounds__(128, 4) void attn_kernel(
    const f16* __restrict__ Qb, const f16* __restrict__ Kb,
    const __bf16* __restrict__ VtA, const __bf16* __restrict__ VtB,
    const f16* __restrict__ relp, float* __restrict__ out) {
    int bid = blockIdx.x;
    int t = threadIdx.x;
    int wv = t >> 6;
    int pb = (bid & 7) * 256 + (bid >> 3);  // XCD-locality swizzle (2048 blocks)
    int pid = pb * 2 + wv;
    int y = pid & 31, x = (pid >> 5) & 31, b = pid >> 10;

    __shared__ __align__(16) __bf16 Pl[2 * 32 * 136];
    __bf16* Plw = Pl + wv * (32 * 136);

    int lane = t & 63;
    int l15 = t & 15, quad = (t >> 4) & 3, kwl = t & 7;

    {   // zero pad cols 112..127 (read by masked kh=7 PV fragments)
        int row = lane >> 1, off = 112 + (lane & 1) * 8;
        *(uint4*)(Plw + row * 136 + off) = (uint4){0u, 0u, 0u, 0u};
    }

    // Q fragments: A[m=qi][k=c]
    f16x8 qf[2];
    {
        const f16* qp = Qb + (size_t)pid * 1024;
        qf[0] = *(const f16x8*)(qp + l15 * 32 + quad * 8);
        qf[1] = *(const f16x8*)(qp + (16 + l15) * 32 + quad * 8);
    }

    // constant "ones" B-fragment for row-sum tile: col l15==0, elements j<7
    bf16x8 onesf;
    {
        __bf16 v = (l15 == 0) ? (__bf16)1.0f : (__bf16)0.0f;
#pragma unroll
        for (int j = 0; j < 7; ++j) onesf[j] = v;
        onesf[7] = (__bf16)0.0f;
    }

    f32x4 acc[2][2];
    f32x4 acc2[2];
#pragma unroll
    for (int m = 0; m < 2; ++m) {
        acc2[m] = (f32x4){0.f, 0.f, 0.f, 0.f};
#pragma unroll
        for (int n = 0; n < 2; ++n) acc[m][n] = (f32x4){0.f, 0.f, 0.f, 0.f};
    }

    int yk = y + kwl;
    if (yk > 37) yk = 37;  // masked column: clamp (finite garbage, V-masked)
    const __bf16* __restrict__ Vsel = (y & 1) ? VtB : VtA;
    int yv = y & ~1;

    for (int chunk = 0; chunk < 4; ++chunk) {
        // ---- scores + exp + bf16 P store (gp = chunk*2 + p8, kh 0..6) ----
        int gp = chunk * 2 + ((t >> 3) & 1);
        const f16* kbp = Kb + ((((size_t)(b * 8 + gp) * 38 + x) * 38 + yk) << 5) + quad * 8;
        const f16* rpp = relp + (size_t)(gp * 7 * 8 + kwl) * 32 + quad * 8;
#pragma unroll
        for (int kh = 0; kh < 7; ++kh) {
            f16x8 kb = *(const f16x8*)kbp;
            f16x8 rp = *(const f16x8*)rpp;
            kbp += 38 * 32;
            rpp += 256;
            kb += rp;  // K' = K + rel'
#pragma unroll
            for (int Mt = 0; Mt < 2; ++Mt) {
                f32x4 d = {0.f, 0.f, 0.f, 0.f};
                d = MFMA_F16(qf[Mt], kb, d);
#pragma unroll
                for (int r = 0; r < 4; ++r) {
                    float e = __expf(fminf(d[r], 80.f));  // clamp: no inf in P
                    Plw[(Mt * 16 + quad * 4 + r) * 136 + kh * 16 + l15] = (__bf16)e;
                }
            }
        }

        // ---- PV accumulate: D[qi][c] += P · V ; row sums via ones tile ----
        int gpv = chunk * 2 + (quad & 1);
        int qh = quad >> 1;
#pragma unroll
        for (int ks = 0; ks < 4; ++ks) {
            bf16x8 af0 = *(const bf16x8*)(Plw + l15 * 136 + ks * 32 + quad * 8);
            bf16x8 af1 = *(const bf16x8*)(Plw + (16 + l15) * 136 + ks * 32 + quad * 8);
            int kh = 2 * ks + qh;
            int khc = (kh > 6) ? 6 : kh;  // masked fragment reads zeros from Pl
#pragma unroll
            for (int t2 = 0; t2 < 2; ++t2) {
                const __bf16* vp =
                    Vsel + (((size_t)(b * 8 + gpv) * 32 + t2 * 16 + l15) * 38 + x + khc) * 40 + yv;
                bf16x8a4 bv8 = *(const bf16x8a4*)vp;
                bv8[7] = (__bf16)0.0f;  // kw=7 mask lives on V, not P
                acc[0][t2] = MFMA_BF16(af0, (bf16x8)bv8, acc[0][t2]);
                acc[1][t2] = MFMA_BF16(af1, (bf16x8)bv8, acc[1][t2]);
            }
            acc2[0] = MFMA_BF16(af0, onesf, acc2[0]);
            acc2[1] = MFMA_BF16(af1, onesf, acc2[1]);
        }
    }

    // ---- epilogue: broadcast row sums from col-0 lanes, 1/sum, head-sum ----
    float inv[2][4];
#pragma unroll
    for (int m = 0; m < 2; ++m)
#pragma unroll
        for (int r = 0; r < 4; ++r)
            inv[m][r] = 1.0f / __shfl(acc2[m][r], t & 48);

#pragma unroll
    for (int Mt = 0; Mt < 2; ++Mt)
#pragma unroll
        for (int t2 = 0; t2 < 2; ++t2) {
            float o = 0.f;
#pragma unroll
            for (int r = 0; r < 4; ++r) o = fmaf(acc[Mt][t2][r], inv[Mt][r], o);
            int g = Mt * 4 + quad;  // qi = Mt*16+quad*4+r -> g lane-local, head = r
            out[(((size_t)(b * 8 + g) * 32 + x) * 32 + y) * 32 + t2 * 16 + l15] = o;
        }
}

// ---------------------------------------------------------------------------
extern "C" void kernel_launch(void* const* d_in, const int* in_sizes, int n_in,
                              void* d_out, int out_size, void* d_ws, size_t ws_size,
                              hipStream_t stream) {
    const float* x     = (const float*)d_in[0];
    const float* wq    = (const float*)d_in[1];
    const float* bq    = (const float*)d_in[2];
    const float* wk    = (const float*)d_in[3];
    const float* bk    = (const float*)d_in[4];
    const float* wv    = (const float*)d_in[5];
    const float* bv    = (const float*)d_in[6];
    const float* rel_h = (const float*)d_in[7];
    const float* rel_w = (const float*)d_in[8];
    float* out = (float*)d_out;

    // ws layout (bytes):
    //   Qb  f16 : 4096*1024*2        = 8,388,608
    //   Kb  f16 : 4*8*38*38*32*2     = 2,957,312
    //   VtA bf16: 4*8*32*38*40*2     = 3,112,960
    //   VtB bf16: 3,112,960
    //   relp f16: 448*32*2           = 28,672
    unsigned char* ws = (unsigned char*)d_ws;
    f16*    Qb   = (f16*)ws;
    f16*    Kb   = (f16*)(ws + 8388608);
    __bf16* VtA  = (__bf16*)(ws + 8388608 + 2957312);
    __bf16* VtB  = (__bf16*)(ws + 8388608 + 2957312 + 3112960);
    f16*    relp = (f16*)(ws + 8388608 + 2957312 + 3112960 + 3112960);

    hipLaunchKernelGGL(produce_kernel, dim3(1217), dim3(256), 0, stream,
                       x, wq, bq, wk, bk, wv, bv, rel_h, rel_w, Qb, Kb, VtA, VtB, relp);
    hipLaunchKernelGGL(attn_kernel, dim3(2048), dim3(128), 0, stream,
                       Qb, Kb, VtA, VtB, relp, out);
}

// Round 7
// 124.983 us; speedup vs baseline: 1.0444x; 1.0444x over previous
//
#include <hip/hip_runtime.h>
#include <math.h>

typedef _Float16 f16;
typedef _Float16 f16x4 __attribute__((ext_vector_type(4)));
typedef _Float16 f16x8 __attribute__((ext_vector_type(8)));
typedef __bf16 bf16x2 __attribute__((ext_vector_type(2)));
typedef __bf16 bf16x4a4 __attribute__((ext_vector_type(4), aligned(4)));
typedef __bf16 bf16x8 __attribute__((ext_vector_type(8)));
typedef __bf16 bf16x8a4 __attribute__((ext_vector_type(8), aligned(4)));
typedef float f32x4 __attribute__((ext_vector_type(4)));

#define MFMA_F16(a, b, c)  __builtin_amdgcn_mfma_f32_16x16x32_f16(a, b, c, 0, 0, 0)
#define MFMA_BF16(a, b, c) __builtin_amdgcn_mfma_f32_16x16x32_bf16(a, b, c, 0, 0, 0)

static __device__ inline f16x8 cvt8(const float* p) {
    const float4* p4 = (const float4*)p;
    float4 u0 = p4[0], u1 = p4[1];
    f16x8 r;
    r[0] = (f16)u0.x; r[1] = (f16)u0.y; r[2] = (f16)u0.z; r[3] = (f16)u0.w;
    r[4] = (f16)u1.x; r[5] = (f16)u1.y; r[6] = (f16)u1.z; r[7] = (f16)u1.w;
    return r;
}

// ---------------------------------------------------------------------------
// Fused producer. Blocks 0..1215: (b,g,hp) rows -> Q,K,V via f16 MFMA.
// Q/K use A=weights so D rows = out-channel -> 4 consecutive channels per
// lane -> packed 8B stores. V uses A=x^T (rows = wp) -> packed wp stores.
// Block 1216 builds relp.
// Layouts: Qb f16 [pos][g*128 + oc]; Kb f16 [b][g][hp][wp][c];
//          VtA bf16 [b][g][c][hp][idx=wp (40)]; VtB same but idx = wp-1.
// ---------------------------------------------------------------------------
__global__ __launch_bounds__(256) void produce_kernel(
    const float* __restrict__ x,
    const float* __restrict__ wq, const float* __restrict__ bq,
    const float* __restrict__ wk, const float* __restrict__ bk,
    const float* __restrict__ wv, const float* __restrict__ bv,
    const float* __restrict__ rel_h, const float* __restrict__ rel_w,
    f16* __restrict__ Qb, f16* __restrict__ Kb,
    __bf16* __restrict__ VtA, __bf16* __restrict__ VtB,
    f16* __restrict__ relp) {
    int bid = blockIdx.x;
    int t = threadIdx.x;

    if (bid == 1216) {  // rel' table: key=(gp*7+kh)*8+kw, channel c
        for (int idx = t; idx < 448 * 32; idx += 256) {
            int c = idx & 31, key = idx >> 5;
            int kw = key & 7, ghk = key >> 3;
            int gp = (ghk * 37) >> 8;
            int kh = ghk - gp * 7;
            float v = 0.f;
            if (kw < 7)
                v = (c < 16) ? rel_h[c * 56 + gp * 7 + kh]
                             : rel_w[(c - 16) * 56 + gp * 7 + kw];
            relp[idx] = (f16)v;
        }
        return;
    }

    int hp = bid % 38, g = (bid / 38) & 7, b = bid / 304;
    bool hin = (hp >= 3 && hp < 35);
    size_t kvbase = (size_t)(b * 8 + g);

    if (!hin) {  // pure-bias row (h padding)
        for (int idx = t; idx < 38 * 32; idx += 256) {
            int wp = idx >> 5, c = idx & 31;
            Kb[((kvbase * 38 + hp) * 38 + wp) * 32 + c] = (f16)bk[g * 32 + c];
        }
        for (int idx = t; idx < 40 * 32; idx += 256) {
            int i = idx >> 5, c = idx & 31;
            size_t vo = ((kvbase * 32 + c) * 38 + hp) * 40;
            __bf16 bb = (__bf16)bv[g * 32 + c];
            VtA[vo + i] = (i < 38) ? bb : (__bf16)0.f;
            VtB[vo + i] = (i < 37) ? bb : (__bf16)0.f;  // idx i = wp i+1
        }
        return;
    }

    int h = hp - 3;
    __shared__ __align__(16) f16 xTl[32 * 40];  // [w][ic], stride 40

    {   // stage x^T (each thread one float4 along w)
        int ic = t >> 3, w = (t & 7) * 4;
        float4 xv = *(const float4*)(x + (((size_t)b * 256 + g * 32 + ic) * 32 + h) * 32 + w);
        xTl[(w + 0) * 40 + ic] = (f16)xv.x;
        xTl[(w + 1) * 40 + ic] = (f16)xv.y;
        xTl[(w + 2) * 40 + ic] = (f16)xv.z;
        xTl[(w + 3) * 40 + ic] = (f16)xv.w;
    }
    __syncthreads();

    int l15 = t & 15, quad = (t >> 4) & 3, wave = t >> 6;

    // x^T fragments: as B for Q/K (n=w), as A for V (m=w). Same lane data.
    f16x8 xf0 = *(const f16x8*)(xTl + l15 * 40 + quad * 8);
    f16x8 xf1 = *(const f16x8*)(xTl + (16 + l15) * 40 + quad * 8);

    // ---- Q: A=wq rows=oc; wave covers oc-tiles wave*2 + {0,1} ----
#pragma unroll
    for (int i = 0; i < 2; ++i) {
        int mq = wave * 2 + i;  // oc-tile 0..7
        f16x8 wf = cvt8(wq + ((size_t)g * 128 + mq * 16 + l15) * 32 + quad * 8);
        float4 b4 = *(const float4*)(bq + g * 128 + mq * 16 + quad * 4);
#pragma unroll
        for (int Nt = 0; Nt < 2; ++Nt) {
            f32x4 d = {0.f, 0.f, 0.f, 0.f};
            d = MFMA_F16(wf, Nt ? xf1 : xf0, d);
            f16x4 q4;
            q4[0] = (f16)(d[0] + b4.x); q4[1] = (f16)(d[1] + b4.y);
            q4[2] = (f16)(d[2] + b4.z); q4[3] = (f16)(d[3] + b4.w);
            int w = Nt * 16 + l15;
            *(f16x4*)(Qb + (size_t)((b * 32 + h) * 32 + w) * 1024 + g * 128 + mq * 16 + quad * 4) = q4;
        }
    }

    if (wave < 2) {
        // ---- K: A=wk rows=c; wave = c-tile ----
        f16x8 wf = cvt8(wk + ((size_t)g * 32 + wave * 16 + l15) * 32 + quad * 8);
        float4 b4 = *(const float4*)(bk + g * 32 + wave * 16 + quad * 4);
#pragma unroll
        for (int Nt = 0; Nt < 2; ++Nt) {
            f32x4 d = {0.f, 0.f, 0.f, 0.f};
            d = MFMA_F16(wf, Nt ? xf1 : xf0, d);
            f16x4 k4;
            k4[0] = (f16)(d[0] + b4.x); k4[1] = (f16)(d[1] + b4.y);
            k4[2] = (f16)(d[2] + b4.z); k4[3] = (f16)(d[3] + b4.w);
            int wp = Nt * 16 + l15 + 3;
            *(f16x4*)(Kb + ((kvbase * 38 + hp) * 38 + wp) * 32 + wave * 16 + quad * 4) = k4;
        }
    } else {
        // ---- V: A=x^T rows=wp; wave-2 = c-tile ----
        int Nt = wave - 2;
        f16x8 wf = cvt8(wv + ((size_t)g * 32 + Nt * 16 + l15) * 32 + quad * 8);
        float bias = bv[g * 32 + Nt * 16 + l15];
        int c = Nt * 16 + l15;
        size_t vo = ((kvbase * 32 + c) * 38 + hp) * 40;
#pragma unroll
        for (int Mt = 0; Mt < 2; ++Mt) {
            f32x4 d = {0.f, 0.f, 0.f, 0.f};
            d = MFMA_F16(Mt ? xf1 : xf0, wf, d);
            __bf16 v0 = (__bf16)(d[0] + bias), v1 = (__bf16)(d[1] + bias);
            __bf16 v2 = (__bf16)(d[2] + bias), v3 = (__bf16)(d[3] + bias);
            int wp0 = Mt * 16 + quad * 4 + 3;  // odd start
            VtA[vo + wp0] = v0;
            bf16x2 mid; mid[0] = v1; mid[1] = v2;
            *(bf16x2*)(VtA + vo + wp0 + 1) = mid;   // idx even -> 4B aligned
            VtA[vo + wp0 + 3] = v3;
            bf16x4a4 p4; p4[0] = v0; p4[1] = v1; p4[2] = v2; p4[3] = v3;
            *(bf16x4a4*)(VtB + vo + wp0 - 1) = p4;  // idx even -> 4B aligned
        }
    }

    // ---- wp borders (bias) + zero pads ----
    for (int idx = t; idx < 192; idx += 256) {
        int wi = idx >> 5, c = idx & 31;
        int wp = (wi < 3) ? wi : (32 + wi);  // {0,1,2,35,36,37}
        Kb[((kvbase * 38 + hp) * 38 + wp) * 32 + c] = (f16)bk[g * 32 + c];
        size_t vo = ((kvbase * 32 + c) * 38 + hp) * 40;
        __bf16 bb = (__bf16)bv[g * 32 + c];
        VtA[vo + wp] = bb;
        if (wp >= 1) VtB[vo + wp - 1] = bb;
    }
    for (int idx = t; idx < 160; idx += 256) {  // VtA idx 38,39; VtB idx 37,38,39
        int c = idx / 5, j = idx % 5;
        size_t vo = ((kvbase * 32 + c) * 38 + hp) * 40;
        if (j < 2) VtA[vo + 38 + j] = (__bf16)0.f;
        else       VtB[vo + 35 + j] = (__bf16)0.f;
    }
}

// ---------------------------------------------------------------------------
// MFMA attention (R5 structure): one wave per position, barrier-free.
// 4 chunks of 2 groups; Pl bf16 [32 qi][136] = 8704 B.
// ---------------------------------------------------------------------------
__global__ __launch_bounds__(64, 4) void attn_kernel(
    const f16* __restrict__ Qb, const f16* __restrict__ Kb,
    const __bf16* __restrict__ VtA, const __bf16* __restrict__ VtB,
    const f16* __restrict__ relp, float* __restrict__ out) {
    int bid = blockIdx.x;
    int pid = (bid & 7) * 512 + (bid >> 3);  // XCD-locality swizzle
    int y = pid & 31, x = (pid >> 5) & 31, b = pid >> 10;

    __shared__ __align__(16) __bf16 Pl[32 * 136];

    int t = threadIdx.x;
    int l15 = t & 15, quad = t >> 4, kwl = t & 7;
    bool mask7 = (kwl == 7);

    {   // zero pad cols 112..127 (read by masked kh=7 PV fragments)
        int row = t >> 1, off = 112 + (t & 1) * 8;
        *(uint4*)(Pl + row * 136 + off) = (uint4){0u, 0u, 0u, 0u};
    }

    // Q fragments: A[m=qi][k=c]
    f16x8 qf[2];
    {
        const f16* qp = Qb + (size_t)pid * 1024;
        qf[0] = *(const f16x8*)(qp + l15 * 32 + quad * 8);
        qf[1] = *(const f16x8*)(qp + (16 + l15) * 32 + quad * 8);
    }

    float fsum[2][4];
#pragma unroll
    for (int m = 0; m < 2; ++m)
#pragma unroll
        for (int r = 0; r < 4; ++r) fsum[m][r] = 0.f;

    f32x4 acc[2][2];
#pragma unroll
    for (int m = 0; m < 2; ++m)
#pragma unroll
        for (int n = 0; n < 2; ++n) acc[m][n] = (f32x4){0.f, 0.f, 0.f, 0.f};

    int yk = y + kwl;
    if (yk > 37) yk = 37;  // masked column: clamp (value discarded)
    const __bf16* __restrict__ Vsel = (y & 1) ? VtB : VtA;
    int yv = y & ~1;

    for (int chunk = 0; chunk < 4; ++chunk) {
        // ---- scores + exp + bf16 P store (gp = chunk*2 + p8, kh 0..6) ----
        int gp = chunk * 2 + ((t >> 3) & 1);
        const f16* kbp = Kb + ((((size_t)(b * 8 + gp) * 38 + x) * 38 + yk) << 5) + quad * 8;
        const f16* rpp = relp + (size_t)(gp * 7 * 8 + kwl) * 32 + quad * 8;
#pragma unroll
        for (int kh = 0; kh < 7; ++kh) {
            f16x8 kb = *(const f16x8*)kbp;
            f16x8 rp = *(const f16x8*)rpp;
            kbp += 38 * 32;
            rpp += 256;
            kb += rp;  // K' = K + rel'
#pragma unroll
            for (int Mt = 0; Mt < 2; ++Mt) {
                f32x4 d = {0.f, 0.f, 0.f, 0.f};
                d = MFMA_F16(qf[Mt], kb, d);
#pragma unroll
                for (int r = 0; r < 4; ++r) {
                    float e = __expf(d[r]);
                    e = mask7 ? 0.f : e;
                    fsum[Mt][r] += e;
                    Pl[(Mt * 16 + quad * 4 + r) * 136 + kh * 16 + l15] = (__bf16)e;
                }
            }
        }

        // ---- PV accumulate: D[qi][c] += P · V ----
        int gpv = chunk * 2 + (quad & 1);
        int qh = quad >> 1;
#pragma unroll
        for (int ks = 0; ks < 4; ++ks) {
            bf16x8 af0 = *(const bf16x8*)(Pl + l15 * 136 + ks * 32 + quad * 8);
            bf16x8 af1 = *(const bf16x8*)(Pl + (16 + l15) * 136 + ks * 32 + quad * 8);
            int kh = 2 * ks + qh;
            int khc = (kh > 6) ? 6 : kh;  // masked fragment reads zeros from Pl
#pragma unroll
            for (int t2 = 0; t2 < 2; ++t2) {
                const __bf16* vp =
                    Vsel + (((size_t)(b * 8 + gpv) * 32 + t2 * 16 + l15) * 38 + x + khc) * 40 + yv;
                bf16x8a4 bv8 = *(const bf16x8a4*)vp;
                bv8[7] = (__bf16)0.0f;  // kw=7 mask on V
                acc[0][t2] = MFMA_BF16(af0, (bf16x8)bv8, acc[0][t2]);
                acc[1][t2] = MFMA_BF16(af1, (bf16x8)bv8, acc[1][t2]);
            }
        }
    }

    // ---- epilogue: reduce fsum over 16 key-cols, 1/sum, head-sum ----
#pragma unroll
    for (int dlt = 1; dlt < 16; dlt <<= 1)
#pragma unroll
        for (int m = 0; m < 2; ++m)
#pragma unroll
            for (int r = 0; r < 4; ++r) fsum[m][r] += __shfl_xor(fsum[m][r], dlt);

    float inv[2][4];
#pragma unroll
    for (int m = 0; m < 2; ++m)
#pragma unroll
        for (int r = 0; r < 4; ++r) inv[m][r] = 1.0f / fsum[m][r];

#pragma unroll
    for (int Mt = 0; Mt < 2; ++Mt)
#pragma unroll
        for (int t2 = 0; t2 < 2; ++t2) {
            float o = 0.f;
#pragma unroll
            for (int r = 0; r < 4; ++r) o = fmaf(acc[Mt][t2][r], inv[Mt][r], o);
            int g = Mt * 4 + quad;  // qi = Mt*16+quad*4+r -> g lane-local, head = r
            out[(((size_t)(b * 8 + g) * 32 + x) * 32 + y) * 32 + t2 * 16 + l15] = o;
        }
}

// ---------------------------------------------------------------------------
extern "C" void kernel_launch(void* const* d_in, const int* in_sizes, int n_in,
                              void* d_out, int out_size, void* d_ws, size_t ws_size,
                              hipStream_t stream) {
    const float* x     = (const float*)d_in[0];
    const float* wq    = (const float*)d_in[1];
    const float* bq    = (const float*)d_in[2];
    const float* wk    = (const float*)d_in[3];
    const float* bk    = (const float*)d_in[4];
    const float* wv    = (const float*)d_in[5];
    const float* bv    = (const float*)d_in[6];
    const float* rel_h = (const float*)d_in[7];
    const float* rel_w = (const float*)d_in[8];
    float* out = (float*)d_out;

    // ws layout (bytes):
    //   Qb  f16 : 4096*1024*2        = 8,388,608
    //   Kb  f16 : 4*8*38*38*32*2     = 2,957,312
    //   VtA bf16: 4*8*32*38*40*2     = 3,112,960
    //   VtB bf16: 3,112,960
    //   relp f16: 448*32*2           = 28,672
    unsigned char* ws = (unsigned char*)d_ws;
    f16*    Qb   = (f16*)ws;
    f16*    Kb   = (f16*)(ws + 8388608);
    __bf16* VtA  = (__bf16*)(ws + 8388608 + 2957312);
    __bf16* VtB  = (__bf16*)(ws + 8388608 + 2957312 + 3112960);
    f16*    relp = (f16*)(ws + 8388608 + 2957312 + 3112960 + 3112960);

    hipLaunchKernelGGL(produce_kernel, dim3(1217), dim3(256), 0, stream,
                       x, wq, bq, wk, bk, wv, bv, rel_h, rel_w, Qb, Kb, VtA, VtB, relp);
    hipLaunchKernelGGL(attn_kernel, dim3(4096), dim3(64), 0, stream,
                       Qb, Kb, VtA, VtB, relp, out);
}